// Round 12
// baseline (241.547 us; speedup 1.0000x reference)
//
#include <hip/hip_runtime.h>
#include <hip/hip_fp16.h>

// out = segment_sum(x[edge_col] * edge_vals[:,None], edge_row) @ W
// N=100000, E=1600000, D=128.
//
// Pipeline: zero -> {GEMM || partition1} (fused dispatch) -> partition2 ->
// bucket_agg. Two-pass small-radix slot-scatter (49 supers x 8 lanes ->
// 3125 fine buckets), fused per-bucket LDS counting-sort + register gather.
//
// Measured lessons (R5-R17):
//  - sub-line scatter runs -> 6x write amp; small radix fixes it (R16).
//  - atomic reservation queue depth matters: 8 lanes/super (R17, -27us).
//  - tiny grids (<2 blk/CU) are latency death.
//  - gemm was LDS-issue-bound: 3 b128 reads / 16 FMAs.
// R18 (this round):
//  - gemm: 128x128 tile, 8x8 acc/thread -> 4 b128 / 64 FMAs (intensity
//    16 vs 10.7). Model: ~31us LDS / ~21us FMA. Same fp32 k-order ->
//    y bitwise identical.
//  - gemm FUSED with p1 in one dispatch (grid 2346: bid%3==0 -> gemm g=bid/3;
//    else p1 pid = bid-1-(bid-1)/3). Compute-bound gemm and latency-bound
//    p1 co-schedule; streams+events are graph-capture-forbidden, so
//    heterogeneous grid is the overlap mechanism.
//  - p2 / bucket_agg / zero unchanged (controls). ws 56.3 MB (unchanged).

#define N_NODES 100000
#define N_EDGES 1600000
#define DIM     128
#define BROWS   32           // rows per fine bucket
#define CB      3125         // fine buckets = N/32 exactly
#define NSUP    49           // supers; super = row>>11
#define LANES   8            // cursor lanes per super
#define NLR     (NSUP * LANES)          // 392 lane regions
#define SLOT1   4608         // recs per lane region (mean 4082, sigma 63; +8 sigma)
#define SLOTCAP2 640         // recs per fine region (mean 512, sigma 22.6)
#define CAP     1024         // bucket_agg LDS capacity
#define OCAP    2048         // overflow list capacity
#define CPAD    16           // u32 stride: one 64B line per cursor

#define EPB1   1024
#define PBLK1  ((N_EDGES + EPB1 - 1) / EPB1)    // 1563
#define CH2    1024
#define CPL    ((SLOT1 + CH2 - 1) / CH2)        // 5 chunks per lane region
#define PBLK2  (NLR * CPL)                      // 1960

#define GBLK   782                               // gemm blocks (128 rows)
#define FBLK   (GBLK * 3)                        // fused grid = 2346

// ---- workspace layout (bytes) ----
// y     @ 0        : N*128 fp16 = 25.6 MB
// ccur1 @ 25600000 : 392 x 64B = 25088
// ccur2 @ 25625088 : 3125 x 64B = 200000
// ocnt  @ 25825088 : 64 B
// obuf  @ 25825152 : 2048 x 16B = 32768
// ebuf1 @ 25857920 : 392*4608 uint2 = 14.45 MB
// ebuf2 @ 40308608 : 3125*640 uint2 = 16.0 MB   (peak 56.3 MB)
#define OFF_CCUR1  25600000
#define OFF_CCUR2  25625088
#define OFF_OCNT   25825088
#define OFF_OBUF   25825152
#define OFF_EBUF1  25857920
#define OFF_EBUF2  40308608

// ---------------------------------------------------------------- zero cursors
__global__ __launch_bounds__(256) void zero_kernel(
    unsigned* ccur1, unsigned* ccur2, unsigned* ocnt)
{
    int i = blockIdx.x * 256 + threadIdx.x;
    if (i < NLR) ccur1[i * CPAD] = 0u;
    if (i < CB)  ccur2[i * CPAD] = 0u;
    if (i == 0)  *ocnt = 0u;
}

// ---------------------------------------------------------------- fused GEMM || partition1
// gemm: 128x128 tile, 256 thr, 8x8 acc. AsT[32][132] fp32 transposed
// (16896B) + Ws[32][128] fp32 (16384B) = 33280B LDS.
// p1: LDS hist[49]+gbase[49] in the same smem.
__global__ __launch_bounds__(256) void gemm_p1_kernel(
    const float* __restrict__ x,
    const float* __restrict__ W,
    __half*      __restrict__ y,
    const int*   __restrict__ erow,
    const int*   __restrict__ ecol,
    const float* __restrict__ eval,
    unsigned*    __restrict__ ccur1,
    unsigned*    __restrict__ ocnt,
    uint4*       __restrict__ obuf,
    uint2*       __restrict__ ebuf1)
{
    __shared__ __align__(16) char smem[33280];
    const unsigned bid = blockIdx.x;
    const int t = threadIdx.x;

    if (bid % 3u == 0u) {
        // ================= GEMM branch =================
        float* AsT = (float*)smem;                 // [kk][r], stride 132
        float* Ws  = (float*)(smem + 16896);       // [kk][c], stride 128
        const int g    = (int)(bid / 3u);          // 0..781
        const int row0 = g * 128;
        const int r0   = (t >> 4) * 8;
        const int c0   = (t & 15) * 8;

        float acc[8][8];
#pragma unroll
        for (int i = 0; i < 8; ++i)
#pragma unroll
            for (int j = 0; j < 8; ++j) acc[i][j] = 0.f;

        for (int k0 = 0; k0 < 128; k0 += 32) {
            // stage A (transposed), guard OOB rows of the last block
#pragma unroll
            for (int i = 0; i < 4; ++i) {
                int li = t + 256 * i;              // 0..1023
                int r  = li >> 3;                  // 0..127
                int kp = li & 7;                   // float4 within row
                int grow = row0 + r;
                float4 a = make_float4(0.f, 0.f, 0.f, 0.f);
                if (grow < N_NODES)
                    a = *(const float4*)(x + (size_t)grow * 128 + k0 + kp * 4);
                AsT[(kp * 4 + 0) * 132 + r] = a.x;
                AsT[(kp * 4 + 1) * 132 + r] = a.y;
                AsT[(kp * 4 + 2) * 132 + r] = a.z;
                AsT[(kp * 4 + 3) * 132 + r] = a.w;
            }
            // stage W
            {
                const float4* Wg = (const float4*)(W + (size_t)k0 * 128);
                float4* Wl = (float4*)Ws;
#pragma unroll
                for (int i = 0; i < 4; ++i) Wl[t + 256 * i] = Wg[t + 256 * i];
            }
            __syncthreads();

#pragma unroll
            for (int kk = 0; kk < 32; ++kk) {
                float4 a0 = *(const float4*)(AsT + kk * 132 + r0);
                float4 a1 = *(const float4*)(AsT + kk * 132 + r0 + 4);
                float4 w0 = *(const float4*)(Ws  + kk * 128 + c0);
                float4 w1 = *(const float4*)(Ws  + kk * 128 + c0 + 4);
                float av[8] = { a0.x, a0.y, a0.z, a0.w, a1.x, a1.y, a1.z, a1.w };
                float wv[8] = { w0.x, w0.y, w0.z, w0.w, w1.x, w1.y, w1.z, w1.w };
#pragma unroll
                for (int i = 0; i < 8; ++i)
#pragma unroll
                    for (int j = 0; j < 8; ++j)
                        acc[i][j] = fmaf(av[i], wv[j], acc[i][j]);
            }
            __syncthreads();
        }

#pragma unroll
        for (int i = 0; i < 8; ++i) {
            int row = row0 + r0 + i;
            if (row < N_NODES) {
                __half2 p0 = __floats2half2_rn(acc[i][0], acc[i][1]);
                __half2 p1 = __floats2half2_rn(acc[i][2], acc[i][3]);
                __half2 p2 = __floats2half2_rn(acc[i][4], acc[i][5]);
                __half2 p3 = __floats2half2_rn(acc[i][6], acc[i][7]);
                uint4 w;
                w.x = *(const unsigned*)&p0;
                w.y = *(const unsigned*)&p1;
                w.z = *(const unsigned*)&p2;
                w.w = *(const unsigned*)&p3;
                *(uint4*)(y + (size_t)row * 128 + c0) = w;
            }
        }
    } else {
        // ================= partition1 branch =================
        unsigned* hist  = (unsigned*)smem;         // [49]
        unsigned* gbase = hist + NSUP;             // [49]
        const unsigned pid = bid - 1u - (bid - 1u) / 3u;   // 0..1563
        if (pid >= PBLK1) return;                  // uniform spare-block exit
        const unsigned e0   = pid * (unsigned)EPB1;
        const unsigned lane = pid & (LANES - 1);

        if (t < NSUP) hist[t] = 0u;
        __syncthreads();

        unsigned r[4], c[4], v[4]; bool ok[4];
#pragma unroll
        for (int k = 0; k < 4; ++k) {
            unsigned e = e0 + (unsigned)k * 256u + t;
            ok[k] = (e < N_EDGES);
            unsigned es = ok[k] ? e : (N_EDGES - 1);
            r[k] = (unsigned)erow[es];
            c[k] = (unsigned)ecol[es];
            v[k] = __float_as_uint(eval[es]);
        }
#pragma unroll
        for (int k = 0; k < 4; ++k)
            if (ok[k]) atomicAdd(&hist[r[k] >> 11], 1u);
        __syncthreads();

        if (t < NSUP) {
            unsigned h = hist[t];
            gbase[t] = h ? atomicAdd(&ccur1[(t * LANES + lane) * CPAD], h) : 0u;
            hist[t] = 0u;                          // reuse as local rank counter
        }
        __syncthreads();

#pragma unroll
        for (int k = 0; k < 4; ++k) {
            if (ok[k]) {
                unsigned s    = r[k] >> 11;
                unsigned rank = atomicAdd(&hist[s], 1u);
                unsigned slot = gbase[s] + rank;
                unsigned q    = s * LANES + lane;
                unsigned xw   = ((r[k] & 2047u) << 17) | c[k];
                if (slot < SLOT1) {
                    ebuf1[(size_t)q * SLOT1 + slot] = make_uint2(xw, v[k]);
                } else {
                    unsigned oi = atomicAdd(ocnt, 1u);
                    if (oi < OCAP) obuf[oi] = make_uint4(xw, v[k], r[k] >> 5, 0u);
                }
            }
        }
    }
}

// ---------------------------------------------------------------- partition pass 2: lane regions -> fine slots
// fine-in-super = (x>>22)&63; global fine f = s*64 + fin.
__global__ __launch_bounds__(256) void partition2_kernel(
    const unsigned* __restrict__ ccur1,
    const uint2*    __restrict__ ebuf1,
    unsigned*       __restrict__ ccur2,
    unsigned*       __restrict__ ocnt,
    uint4*          __restrict__ obuf,
    uint2*          __restrict__ ebuf2)
{
    __shared__ unsigned hist[64];
    __shared__ unsigned gbase[64];
    const int t  = threadIdx.x;
    const int q  = blockIdx.x / CPL;                // 392 lane regions
    const int ch = blockIdx.x % CPL;                // 5 chunks
    const int s  = q >> 3;                          // super

    unsigned cnt = ccur1[q * CPAD];
    if (cnt > SLOT1) cnt = SLOT1;
    const unsigned base = (unsigned)ch * CH2;
    if (base >= cnt) return;                        // uniform across block
    const unsigned m = (cnt - base < CH2) ? (cnt - base) : CH2;

    if (t < 64) hist[t] = 0u;
    __syncthreads();

    uint2 rec[4]; bool ok[4];
#pragma unroll
    for (int k = 0; k < 4; ++k) {
        unsigned idx = (unsigned)k * 256u + t;
        ok[k] = (idx < m);
        rec[k] = ok[k] ? ebuf1[(size_t)q * SLOT1 + base + idx] : make_uint2(0u, 0u);
    }
#pragma unroll
    for (int k = 0; k < 4; ++k)
        if (ok[k]) atomicAdd(&hist[(rec[k].x >> 22) & 63u], 1u);
    __syncthreads();

    if (t < 64) {
        unsigned h = hist[t];
        gbase[t] = h ? atomicAdd(&ccur2[(s * 64 + t) * CPAD], h) : 0u;
        hist[t] = 0u;                            // reuse as local rank counter
    }
    __syncthreads();

#pragma unroll
    for (int k = 0; k < 4; ++k) {
        if (ok[k]) {
            unsigned fin  = (rec[k].x >> 22) & 63u;
            unsigned rank = atomicAdd(&hist[fin], 1u);
            unsigned slot = gbase[fin] + rank;
            unsigned f    = (unsigned)s * 64u + fin;
            if (slot < SLOTCAP2) {
                ebuf2[(size_t)f * SLOTCAP2 + slot] = rec[k];
            } else {
                unsigned oi = atomicAdd(ocnt, 1u);
                if (oi < OCAP) obuf[oi] = make_uint4(rec[k].x, rec[k].y, f, 0u);
            }
        }
    }
}

// ---------------------------------------------------------------- bucket agg (control)
// one block per fine bucket (32 rows): stage slot slice + overflow in LDS,
// counting-sort by row ((x>>17)&31), wave-per-row register gather of y rows.
__global__ __launch_bounds__(256) void bucket_agg_kernel(
    const __half*   __restrict__ y,
    const unsigned* __restrict__ ccur2,
    const unsigned* __restrict__ ocnt,
    const uint4*    __restrict__ obuf,
    const uint2*    __restrict__ ebuf2,
    float*          __restrict__ out)
{
    __shared__ uint2    raw[CAP];        // 8 KB
    __shared__ uint2    sorted[CAP];     // 8 KB
    __shared__ unsigned hist[BROWS];
    __shared__ unsigned sstart[BROWS];
    __shared__ unsigned scur[BROWS];
    __shared__ unsigned extn;

    const int t    = threadIdx.x;
    const int b    = blockIdx.x;                 // 3125 blocks
    const int lane = t & 63;
    const int wv   = t >> 6;

    const unsigned cnt = ccur2[b * CPAD];
    const unsigned n   = (cnt < SLOTCAP2) ? cnt : SLOTCAP2;
    const size_t   base = (size_t)b * SLOTCAP2;

    if (t == 0) extn = 0u;
    if (t < BROWS) hist[t] = 0u;
    __syncthreads();

    for (unsigned i = t; i < n; i += 256) {
        uint2 rec = ebuf2[base + i];
        raw[i] = rec;
        atomicAdd(&hist[(rec.x >> 17) & 31u], 1u);
    }

    // drain overflow list (typically empty: one load of *ocnt)
    unsigned oc = *ocnt;
    if (oc > OCAP) oc = OCAP;
    for (unsigned i = t; i < oc; i += 256) {
        uint4 o = obuf[i];
        if (o.z == (unsigned)b) {
            unsigned p = atomicAdd(&extn, 1u);
            if (n + p < CAP) {
                raw[n + p] = make_uint2(o.x, o.y);
                atomicAdd(&hist[(o.x >> 17) & 31u], 1u);
            }
        }
    }
    __syncthreads();

    unsigned m = n + extn;
    if (m > CAP) m = CAP;

    if (t < 64) {                                // scan 32 counters, wave 0
        unsigned v = (t < BROWS) ? hist[t] : 0u;
        unsigned inc = v;
#pragma unroll
        for (int d = 1; d < 64; d <<= 1) {
            unsigned o = __shfl_up(inc, d);
            if (t >= d) inc += o;
        }
        unsigned excl = inc - v;
        if (t < BROWS) { sstart[t] = excl; scur[t] = excl; }
    }
    __syncthreads();

    for (unsigned i = t; i < m; i += 256) {
        uint2 rec = raw[i];
        unsigned p = atomicAdd(&scur[(rec.x >> 17) & 31u], 1u);
        sorted[p] = rec;
    }
    __syncthreads();

    for (int r = wv; r < BROWS; r += 4) {
        int row = b * BROWS + r;
        if (row >= N_NODES) break;
        float ax = 0.f, ay = 0.f;
        unsigned j = sstart[r], e = scur[r];
        for (; j + 4 <= e; j += 4) {
            uint2 r0 = sorted[j + 0];
            uint2 r1 = sorted[j + 1];
            uint2 r2 = sorted[j + 2];
            uint2 r3 = sorted[j + 3];
            const __half2 h0 = *((const __half2*)(y + (size_t)(r0.x & 0x1FFFFu) * 128) + lane);
            const __half2 h1 = *((const __half2*)(y + (size_t)(r1.x & 0x1FFFFu) * 128) + lane);
            const __half2 h2 = *((const __half2*)(y + (size_t)(r2.x & 0x1FFFFu) * 128) + lane);
            const __half2 h3 = *((const __half2*)(y + (size_t)(r3.x & 0x1FFFFu) * 128) + lane);
            float v0 = __uint_as_float(r0.y);
            float v1 = __uint_as_float(r1.y);
            float v2 = __uint_as_float(r2.y);
            float v3 = __uint_as_float(r3.y);
            float2 f0 = __half22float2(h0);
            float2 f1 = __half22float2(h1);
            float2 f2 = __half22float2(h2);
            float2 f3 = __half22float2(h3);
            ax = fmaf(f0.x, v0, ax); ay = fmaf(f0.y, v0, ay);
            ax = fmaf(f1.x, v1, ax); ay = fmaf(f1.y, v1, ay);
            ax = fmaf(f2.x, v2, ax); ay = fmaf(f2.y, v2, ay);
            ax = fmaf(f3.x, v3, ax); ay = fmaf(f3.y, v3, ay);
        }
        for (; j < e; ++j) {
            uint2 rr = sorted[j];
            const __half2 h = *((const __half2*)(y + (size_t)(rr.x & 0x1FFFFu) * 128) + lane);
            float v = __uint_as_float(rr.y);
            float2 f = __half22float2(h);
            ax = fmaf(f.x, v, ax); ay = fmaf(f.y, v, ay);
        }
        *((float2*)(out + (size_t)row * 128) + lane) = make_float2(ax, ay);
    }
}

// ---------------------------------------------------------------- launch
extern "C" void kernel_launch(void* const* d_in, const int* in_sizes, int n_in,
                              void* d_out, int out_size, void* d_ws, size_t ws_size,
                              hipStream_t stream) {
    const float* x    = (const float*)d_in[0];
    const int*   erow = (const int*)d_in[1];
    const int*   ecol = (const int*)d_in[2];
    const float* eval = (const float*)d_in[3];
    const float* W    = (const float*)d_in[4];
    float* out = (float*)d_out;

    char* ws = (char*)d_ws;
    __half*   y     = (__half*)  (ws);
    unsigned* ccur1 = (unsigned*)(ws + OFF_CCUR1);
    unsigned* ccur2 = (unsigned*)(ws + OFF_CCUR2);
    unsigned* ocnt  = (unsigned*)(ws + OFF_OCNT);
    uint4*    obuf  = (uint4*)   (ws + OFF_OBUF);
    uint2*    ebuf1 = (uint2*)   (ws + OFF_EBUF1);
    uint2*    ebuf2 = (uint2*)   (ws + OFF_EBUF2);

    zero_kernel<<<(CB + 255) / 256, 256, 0, stream>>>(ccur1, ccur2, ocnt);
    gemm_p1_kernel<<<FBLK, 256, 0, stream>>>(x, W, y, erow, ecol, eval,
                                             ccur1, ocnt, obuf, ebuf1);
    partition2_kernel<<<PBLK2, 256, 0, stream>>>(ccur1, ebuf1, ccur2, ocnt, obuf, ebuf2);
    bucket_agg_kernel<<<CB, 256, 0, stream>>>(y, ccur2, ocnt, obuf, ebuf2, out);
}